// Round 14
// baseline (123.124 us; speedup 1.0000x reference)
//
#include <hip/hip_runtime.h>
#include <hip/hip_bf16.h>

#define BB 2
#define TT 2048
#define DM 1024
#define NH 16
#define HD 64
#define BT (BB*TT)
#define SC2 0.18033688011112042f   // 0.125 / ln(2)

typedef unsigned short u16;
typedef __attribute__((ext_vector_type(8))) short short8;
typedef __attribute__((ext_vector_type(4))) float f32x4;

__device__ __forceinline__ u16 f2b(float f){
  unsigned u = __builtin_bit_cast(unsigned, f);
  u += 0x7FFFu + ((u >> 16) & 1u);
  return (u16)(u >> 16);
}
__device__ __forceinline__ float b2f(u16 h){
  unsigned u = ((unsigned)h) << 16;
  return __builtin_bit_cast(float, u);
}

__device__ __forceinline__ void gll16(const u16* g, u16* l){
  __builtin_amdgcn_global_load_lds((const __attribute__((address_space(1))) void*)g,
                                   (__attribute__((address_space(3))) void*)l, 16, 0, 0);
}

// ---------------- fused f32 -> bf16 conversion (X + 4 weights) ----------------
__global__ __launch_bounds__(256) void cvt_all_kernel(const float* __restrict__ X,
                                                      const float* __restrict__ w0,
                                                      const float* __restrict__ w1,
                                                      const float* __restrict__ w2,
                                                      const float* __restrict__ w3,
                                                      u16* __restrict__ Xb,
                                                      u16* __restrict__ Wb){
  const int b = blockIdx.x;
  const float* src;
  u16* dst;
  int i;
  if (b < 4096){
    src = X; dst = Xb; i = b*256 + threadIdx.x;
  } else {
    const int bb = b - 4096;
    const int seg = bb >> 10;
    src = (seg==0)?w0:(seg==1)?w1:(seg==2)?w2:w3;
    dst = Wb + (size_t)seg*DM*DM;
    i = (bb & 1023)*256 + threadIdx.x;
  }
  const float4 v = *(const float4*)(src + (size_t)i*4);
  ushort4 o;
  o.x = f2b(v.x); o.y = f2b(v.y); o.z = f2b(v.z); o.w = f2b(v.w);
  *(ushort4*)(dst + (size_t)i*4) = o;
}

// ---- 128x128-tile LDS-staged GEMM (QKV), counted-vmcnt two-barrier pipeline ----
#define FRAG(buf, row) (*(const short8*)((buf) + (size_t)(row)*32 + ((g ^ (((row)>>1)&3))*8)))

__global__ __launch_bounds__(256) void gemm_qkv(const u16* __restrict__ A,
                                                const u16* __restrict__ W,
                                                u16* __restrict__ Ybf){
  __shared__ u16 sA0[4096], sB0[4096], sA1[4096], sB1[4096];
  const int tid = threadIdx.x;
  const int lane = tid & 63;
  const int wave = tid >> 6;
  const int r = lane & 15, g = lane >> 4;
  const int wr = wave >> 1, wc = wave & 1;
  const int m0 = blockIdx.y << 7;
  const int nn0 = blockIdx.x << 7;

  const int srow = tid >> 2;
  const int lcol = (((tid & 3) ^ ((srow >> 1) & 3))) * 8;

  const u16* gA0 = A + (size_t)(m0 + srow)*DM + lcol;
  const u16* gA1 = gA0 + (size_t)64*DM;
  const u16* gB0 = W + (size_t)(nn0 + srow)*DM + lcol;
  const u16* gB1 = gB0 + (size_t)64*DM;

  f32x4 acc[4][4];
  #pragma unroll
  for (int i=0;i<4;i++)
    #pragma unroll
    for (int j=0;j<4;j++) acc[i][j] = (f32x4){0.f,0.f,0.f,0.f};

#define STAGE(SA, SB, koff) { \
    gll16(gA0 + (koff), SA + (size_t)tid*8); \
    gll16(gA1 + (koff), SA + 2048 + (size_t)tid*8); \
    gll16(gB0 + (koff), SB + (size_t)tid*8); \
    gll16(gB1 + (koff), SB + 2048 + (size_t)tid*8); }

#define COMPUTE(SA, SB) { \
    short8 af[4], bf[4]; \
    _Pragma("unroll") \
    for (int f=0; f<4; f++){ \
      af[f] = FRAG(SA, wr*64 + f*16 + r); \
      bf[f] = FRAG(SB, wc*64 + f*16 + r); \
    } \
    _Pragma("unroll") \
    for (int fr=0; fr<4; fr++) \
      _Pragma("unroll") \
      for (int fn=0; fn<4; fn++) \
        acc[fr][fn] = __builtin_amdgcn_mfma_f32_16x16x32_bf16(af[fr], bf[fn], acc[fr][fn], 0,0,0); }

  STAGE(sA0, sB0, 0);
  STAGE(sA1, sB1, 32);
  asm volatile("" ::: "memory");

  for (int t = 0; t < 32; t += 2){
    asm volatile("s_waitcnt vmcnt(4)" ::: "memory");
    __builtin_amdgcn_s_barrier();
    COMPUTE(sA0, sB0);
    __builtin_amdgcn_s_barrier();
    if (t + 2 < 32) STAGE(sA0, sB0, (t+2)*32);
    if (t + 3 < 32){
      asm volatile("s_waitcnt vmcnt(4)" ::: "memory");
    } else {
      asm volatile("s_waitcnt vmcnt(0)" ::: "memory");
    }
    __builtin_amdgcn_s_barrier();
    COMPUTE(sA1, sB1);
    __builtin_amdgcn_s_barrier();
    if (t + 3 < 32) STAGE(sA1, sB1, (t+3)*32);
  }

  #pragma unroll
  for (int fr=0; fr<4; fr++){
    #pragma unroll
    for (int i=0;i<4;i++){
      const int m = m0 + wr*64 + fr*16 + g*4 + i;
      #pragma unroll
      for (int fn=0; fn<4; fn++){
        const int nn = nn0 + wc*64 + fn*16 + r;
        Ybf[(size_t)(nn >> 10)*BT*DM + (size_t)m*DM + (nn & 1023)] = f2b(acc[fr][fn][i]);
      }
    }
  }
#undef STAGE
#undef COMPUTE
}

// ---- 64x128-tile output GEMM (f32 out): grid (8,64) -> 2 blocks/CU ----
__global__ __launch_bounds__(256) void gemm_out64(const u16* __restrict__ A,
                                                  const u16* __restrict__ W,
                                                  float* __restrict__ Yf){
  __shared__ u16 sA0[2048], sB0[4096], sA1[2048], sB1[4096];
  const int tid = threadIdx.x;
  const int lane = tid & 63;
  const int wave = tid >> 6;
  const int r = lane & 15, g = lane >> 4;
  const int wr = wave >> 1, wc = wave & 1;     // 2x2 waves over 64m x 128n
  const int m0 = blockIdx.y << 6;
  const int nn0 = blockIdx.x << 7;

  const int srow = tid >> 2;
  const int lcol = (((tid & 3) ^ ((srow >> 1) & 3))) * 8;

  const u16* gA0 = A + (size_t)(m0 + srow)*DM + lcol;
  const u16* gB0 = W + (size_t)(nn0 + srow)*DM + lcol;
  const u16* gB1 = gB0 + (size_t)64*DM;

  f32x4 acc[2][4];
  #pragma unroll
  for (int i=0;i<2;i++)
    #pragma unroll
    for (int j=0;j<4;j++) acc[i][j] = (f32x4){0.f,0.f,0.f,0.f};

#define STAGEO(SA, SB, koff) { \
    gll16(gA0 + (koff), SA + (size_t)tid*8); \
    gll16(gB0 + (koff), SB + (size_t)tid*8); \
    gll16(gB1 + (koff), SB + 2048 + (size_t)tid*8); }

#define COMPUTEO(SA, SB) { \
    short8 af[2], bf[4]; \
    _Pragma("unroll") \
    for (int f=0; f<2; f++) af[f] = FRAG(SA, wr*32 + f*16 + r); \
    _Pragma("unroll") \
    for (int f=0; f<4; f++) bf[f] = FRAG(SB, wc*64 + f*16 + r); \
    _Pragma("unroll") \
    for (int fr=0; fr<2; fr++) \
      _Pragma("unroll") \
      for (int fn=0; fn<4; fn++) \
        acc[fr][fn] = __builtin_amdgcn_mfma_f32_16x16x32_bf16(af[fr], bf[fn], acc[fr][fn], 0,0,0); }

  STAGEO(sA0, sB0, 0);
  STAGEO(sA1, sB1, 32);
  asm volatile("" ::: "memory");

  for (int t = 0; t < 32; t += 2){
    asm volatile("s_waitcnt vmcnt(3)" ::: "memory");
    __builtin_amdgcn_s_barrier();
    COMPUTEO(sA0, sB0);
    __builtin_amdgcn_s_barrier();
    if (t + 2 < 32) STAGEO(sA0, sB0, (t+2)*32);
    if (t + 3 < 32){
      asm volatile("s_waitcnt vmcnt(3)" ::: "memory");
    } else {
      asm volatile("s_waitcnt vmcnt(0)" ::: "memory");
    }
    __builtin_amdgcn_s_barrier();
    COMPUTEO(sA1, sB1);
    __builtin_amdgcn_s_barrier();
    if (t + 3 < 32) STAGEO(sA1, sB1, (t+3)*32);
  }

  #pragma unroll
  for (int fr=0; fr<2; fr++){
    #pragma unroll
    for (int i=0;i<4;i++){
      const int m = m0 + wr*32 + fr*16 + g*4 + i;
      #pragma unroll
      for (int fn=0; fn<4; fn++){
        const int nn = nn0 + wc*64 + fn*16 + r;
        Yf[(size_t)m*DM + nn] = acc[fr][fn][i];
      }
    }
  }
#undef STAGEO
#undef COMPUTEO
}

// ------- fused RoPE (blocks 0..511, Q pre-scaled) + V transpose (512..1535) -------
__global__ __launch_bounds__(256) void rope_vt_kernel(u16* __restrict__ Qb,
                                                      u16* __restrict__ Kb,
                                                      const int* __restrict__ pos,
                                                      const u16* __restrict__ Vb,
                                                      u16* __restrict__ Vt){
  __shared__ u16 tile[64][72];
  if (blockIdx.x < 512){
    const int t = blockIdx.x*256 + threadIdx.x;
    const int m = t >> 5;
    const int fi = t & 31;
    const float invf = __expf(-(float)fi * 0.28782313662425575f);
    float s, c;
    sincosf((float)pos[m] * invf, &s, &c);
    const float cq = c*SC2, sq = s*SC2;
    const size_t base = (size_t)m*DM + fi*2;
    #pragma unroll
    for (int h=0; h<NH; h++){
      const size_t a = base + h*HD;
      {
        const float x0 = b2f(Qb[a]), x1 = b2f(Qb[a+1]);
        Qb[a]   = f2b(cq*x0 - sq*x1);
        Qb[a+1] = f2b(cq*x1 + sq*x0);
      }
      {
        const float x0 = b2f(Kb[a]), x1 = b2f(Kb[a+1]);
        Kb[a]   = f2b(c*x0 - s*x1);
        Kb[a+1] = f2b(c*x1 + s*x0);
      }
    }
  } else {
    const int bidx = blockIdx.x - 512;
    const int bh = bidx >> 5;
    const int sc = bidx & 31;
    const int bq = bh >> 4, h = bh & 15;
    const int s0 = sc*64;
    {
      const int row = threadIdx.x >> 3;
      const int c8 = (threadIdx.x & 7)*8;
      #pragma unroll
      for (int rr = 0; rr < 64; rr += 32){
        const short8 v = *(const short8*)(Vb + (size_t)(bq*TT + s0 + row + rr)*DM + h*HD + c8);
        *(short8*)(&tile[row+rr][c8]) = v;
      }
    }
    __syncthreads();
    {
      const int d = threadIdx.x >> 3;
      const int s8 = (threadIdx.x & 7)*8;
      #pragma unroll
      for (int dd = 0; dd < 64; dd += 32){
        short8 ov;
        #pragma unroll
        for (int j=0;j<8;j++){
          const int sl = s8 + j;
          const int w = sl & 31;
          const int slog = (sl & 32) + (w >> 1) + ((w & 1) << 4);
          ov[j] = (short)tile[slog][d+dd];
        }
        *(short8*)(Vt + ((size_t)bh*HD + d + dd)*TT + s0 + s8) = ov;
      }
    }
  }
}

// ---------- causal flash attention: 8-wave blocks, KVBLK=128, counted-vmcnt ----------
template<bool MASKED>
__device__ __forceinline__ void proc_fast(
    const short8 qf0, const short8 qf1,
    const short8 k00, const short8 k01, const short8 k10, const short8 k11,
    const short8 v0, const short8 v1, const short8 v2, const short8 v3,
    f32x4& o0, f32x4& o1, f32x4& o2, f32x4& o3,
    float (&lsum)[4],
    const int q0, const int s0, const int r, const int g,
    u16 (*pbuf)[40])
{
  f32x4 sa0={0,0,0,0}, sa1={0,0,0,0};
  __builtin_amdgcn_s_setprio(1);
  sa0 = __builtin_amdgcn_mfma_f32_16x16x32_bf16(qf0, k00, sa0, 0,0,0);
  sa0 = __builtin_amdgcn_mfma_f32_16x16x32_bf16(qf1, k01, sa0, 0,0,0);
  sa1 = __builtin_amdgcn_mfma_f32_16x16x32_bf16(qf0, k10, sa1, 0,0,0);
  sa1 = __builtin_amdgcn_mfma_f32_16x16x32_bf16(qf1, k11, sa1, 0,0,0);
  __builtin_amdgcn_s_setprio(0);
  #pragma unroll
  for (int i=0;i<4;i++){
    float a = sa0[i], b = sa1[i];
    if (MASKED){
      const int q = q0 + g*4 + i;
      a = (s0 + r      <= q) ? a : -3.0e38f;
      b = (s0 + 16 + r <= q) ? b : -3.0e38f;
    }
    const float p0 = exp2f(a);
    const float p1 = exp2f(b);
    lsum[i] += p0 + p1;
    unsigned w;
    asm("v_cvt_pk_bf16_f32 %0, %1, %2" : "=v"(w) : "v"(p0), "v"(p1));
    *(unsigned*)(&pbuf[g*4+i][r*2]) = w;   // keys r (lo half), 16+r (hi half) interleaved
  }
  const short8 pf = *(const short8*)(&pbuf[r][g*8]);
  __builtin_amdgcn_s_setprio(1);
  o0 = __builtin_amdgcn_mfma_f32_16x16x32_bf16(pf, v0, o0, 0,0,0);
  o1 = __builtin_amdgcn_mfma_f32_16x16x32_bf16(pf, v1, o1, 0,0,0);
  o2 = __builtin_amdgcn_mfma_f32_16x16x32_bf16(pf, v2, o2, 0,0,0);
  o3 = __builtin_amdgcn_mfma_f32_16x16x32_bf16(pf, v3, o3, 0,0,0);
  __builtin_amdgcn_s_setprio(0);
}

__global__ __launch_bounds__(512) void attn_kernel(const u16* __restrict__ Qb,
                                                   const u16* __restrict__ Kb,
                                                   const u16* __restrict__ Vt,
                                                   u16* __restrict__ Ob){
  __shared__ u16 KVs[2][16384];      // [buf][ K: 128x64 | V^T: 64x128 ], slot-swizzled
  __shared__ u16 Plds[8][16][40];
  const int tid = threadIdx.x;
  const int lane = tid & 63;
  const int wave = tid >> 6;         // 0..7
  const int wq = wave & 3;           // q-row group
  const int par = wave >> 2;         // 64-key-half parity within 128-block
  const int r = lane & 15, g = lane >> 4;

  const int bh = blockIdx.x;             // 0..31  (fast dim -> XCD L2 locality)
  const int pp = blockIdx.y;             // 0..15  (panel pair)
  const int bq = bh >> 4, h = bh & 15;
  const int lo = pp, hi = 31 - pp;
  const int w0A = lo*64 + wq*16;
  const int w0B = hi*64 + wq*16;
  const int sAd = (w0A >> 5) << 5;       // diagonal 32-block start for tile A
  const int sBd = (w0B >> 5) << 5;
  const int nb = (hi + 2) >> 1;          // 128-key stage iterations (>=9)

  // ---- Q fragments (pre-scaled by SC2 in rope) ----
  const u16* QrowA = Qb + (size_t)(bq*TT + w0A + r)*DM + h*HD;
  const u16* QrowB = Qb + (size_t)(bq*TT + w0B + r)*DM + h*HD;
  const short8 qA0 = *(const short8*)(QrowA + g*8);
  const short8 qA1 = *(const short8*)(QrowA + 32 + g*8);
  const short8 qB0 = *(const short8*)(QrowB + g*8);
  const short8 qB1 = *(const short8*)(QrowB + 32 + g*8);

  // ---- staging sources (pre-swizzled) ----
  const int srowK = tid >> 3;                    // 0..63
  const int qk = tid & 7;
  const u16* KsrcA = Kb + (size_t)(bq*TT + srowK)*DM + h*HD + ((qk ^ (srowK & 7))*8);
  const int srowV = tid >> 4;                    // 0..31
  const int qv = tid & 15;
  const int vswz = ((qv & 8) | ((qv & 7) ^ (srowV & 7)))*8;
  const u16* VsrcA = Vt + (size_t)bh*HD*TT + (size_t)srowV*TT + vswz;

  f32x4 oA0={0,0,0,0}, oA1={0,0,0,0}, oA2={0,0,0,0}, oA3={0,0,0,0};
  f32x4 oB0={0,0,0,0}, oB1={0,0,0,0}, oB2={0,0,0,0}, oB3={0,0,0,0};
  float lA[4] = {0.f,0.f,0.f,0.f}, lB[4] = {0.f,0.f,0.f,0.f};

#define STAGEKV(B, S) { \
    gll16(KsrcA + (size_t)(S)*DM,        &KVs[B][0]     + (size_t)tid*8); \
    gll16(KsrcA + (size_t)((S)+64)*DM,   &KVs[B][4096]  + (size_t)tid*8); \
    gll16(VsrcA + (S),                   &KVs[B][8192]  + (size_t)tid*8); \
    gll16(VsrcA + (size_t)32*TT + (S),   &KVs[B][12288] + (size_t)tid*8); }

  STAGEKV(0, 0);
  STAGEKV(1, 128);             // nb >= 9 always
  asm volatile("" ::: "memory");

  for (int ib = 0; ib < nb; ib++){
    const int cur = ib & 1;
    if (ib + 1 < nb){
      asm volatile("s_waitcnt vmcnt(4)" ::: "memory");
    } else {
      asm volatile("s_waitcnt vmcnt(0)" ::: "memory");
    }
    __builtin_amdgcn_s_barrier();

    const u16* kb_ = KVs[cur];
    const u16* vb_ = KVs[cur] + 8192;
    const int ph0 = (g ^ (r & 7))*8;
    const int ph1 = ((g + 4) ^ (r & 7))*8;
    #pragma unroll
    for (int hf = 0; hf < 2; hf++){
      const int rkb = par*64 + hf*32;        // key offset within 128-block
      const int s0 = ib*128 + rkb;           // absolute key base (wave-uniform)
      if (s0 <= sBd){
        const int rb = rkb + r;
        const short8 k00 = *(const short8*)(kb_ + (size_t)rb*64 + ph0);
        const short8 k01 = *(const short8*)(kb_ + (size_t)rb*64 + ph1);
        const short8 k10 = *(const short8*)(kb_ + (size_t)(rb+16)*64 + ph0);
        const short8 k11 = *(const short8*)(kb_ + (size_t)(rb+16)*64 + ph1);
        const int c8 = (rkb >> 3) + g;       // 0..15
        const int vc = ((c8 & 8) | ((c8 & 7) ^ (r & 7)))*8;
        const short8 v0 = *(const short8*)(vb_ + (size_t)(r     )*128 + vc);
        const short8 v1 = *(const short8*)(vb_ + (size_t)(16 + r)*128 + vc);
        const short8 v2 = *(const short8*)(vb_ + (size_t)(32 + r)*128 + vc);
        const short8 v3 = *(const short8*)(vb_ + (size_t)(48 + r)*128 + vc);
        if (s0 <= sAd){
          if (s0 == sAd) proc_fast<true >(qA0,qA1,k00,k01,k10,k11,v0,v1,v2,v3,
                                          oA0,oA1,oA2,oA3,lA,w0A,s0,r,g,Plds[wave]);
          else           proc_fast<false>(qA0,qA1,k00,k01,k10,k11,v0,v1,v2,v3,
                                          oA0,oA1,oA2,oA3,lA,w0A,s0,r,g,Plds[wave]);
        }
        if (s0 == sBd) proc_fast<true >(qB0,qB1,k00,k01,k10,k11,v0,v1,v2,v3,
                                        oB0,oB1,oB2,oB3,lB,w0B,s0,r,g,Plds[wave]);
        else           proc_fast<false>(qB0,qB1,k00,k01,k10,k11,v0,v1,v2,v3,
                                        oB0,oB1,oB2,oB3,lB,w0B,s0,r,g,Plds[wave]);
      }
    }
    __builtin_amdgcn_s_barrier();
    if (ib + 2 < nb) STAGEKV(cur, (ib + 2)*128);
  }
#undef STAGEKV

  // ---- parity merge (pure sums; m==0 so no max/exp needed) ----
  __syncthreads();
  float* scr = (float*)&KVs[0][0];           // 20 KB scratch per phase
  const int mbase = wq*20*64 + lane;
  if (par == 1){
    #pragma unroll
    for (int i=0;i<4;i++){
      scr[mbase + (0*4+i)*64] = oA0[i];
      scr[mbase + (1*4+i)*64] = oA1[i];
      scr[mbase + (2*4+i)*64] = oA2[i];
      scr[mbase + (3*4+i)*64] = oA3[i];
      scr[mbase + (16+i)*64]  = lA[i];
    }
  }
  __syncthreads();
  if (par == 0){
    #pragma unroll
    for (int i=0;i<4;i++){
      oA0[i] += scr[mbase + (0*4+i)*64];
      oA1[i] += scr[mbase + (1*4+i)*64];
      oA2[i] += scr[mbase + (2*4+i)*64];
      oA3[i] += scr[mbase + (3*4+i)*64];
      lA[i]  += scr[mbase + (16+i)*64];
    }
  }
  __syncthreads();
  if (par == 1){
    #pragma unroll
    for (int i=0;i<4;i++){
      scr[mbase + (0*4+i)*64] = oB0[i];
      scr[mbase + (1*4+i)*64] = oB1[i];
      scr[mbase + (2*4+i)*64] = oB2[i];
      scr[mbase + (3*4+i)*64] = oB3[i];
      scr[mbase + (16+i)*64]  = lB[i];
    }
  }
  __syncthreads();
  if (par == 0){
    #pragma unroll
    for (int i=0;i<4;i++){
      oB0[i] += scr[mbase + (0*4+i)*64];
      oB1[i] += scr[mbase + (1*4+i)*64];
      oB2[i] += scr[mbase + (2*4+i)*64];
      oB3[i] += scr[mbase + (3*4+i)*64];
      lB[i]  += scr[mbase + (16+i)*64];
    }
    #pragma unroll
    for (int off=8; off>0; off>>=1){
      #pragma unroll
      for (int i=0;i<4;i++){
        lA[i] += __shfl_xor(lA[i], off);
        lB[i] += __shfl_xor(lB[i], off);
      }
    }
    float invA[4], invB[4];
    #pragma unroll
    for (int i=0;i<4;i++){ invA[i] = 1.0f/lA[i]; invB[i] = 1.0f/lB[i]; }
    #pragma unroll
    for (int i=0;i<4;i++){
      const size_t rowA = (size_t)(bq*TT + w0A + g*4 + i)*DM + h*HD;
      Ob[rowA + r]      = f2b(oA0[i]*invA[i]);
      Ob[rowA + 16 + r] = f2b(oA1[i]*invA[i]);
      Ob[rowA + 32 + r] = f2b(oA2[i]*invA[i]);
      Ob[rowA + 48 + r] = f2b(oA3[i]*invA[i]);
      const size_t rowB = (size_t)(bq*TT + w0B + g*4 + i)*DM + h*HD;
      Ob[rowB + r]      = f2b(oB0[i]*invB[i]);
      Ob[rowB + 16 + r] = f2b(oB1[i]*invB[i]);
      Ob[rowB + 32 + r] = f2b(oB2[i]*invB[i]);
      Ob[rowB + 48 + r] = f2b(oB3[i]*invB[i]);
    }
  }
}

extern "C" void kernel_launch(void* const* d_in, const int* in_sizes, int n_in,
                              void* d_out, int out_size, void* d_ws, size_t ws_size,
                              hipStream_t stream) {
  const float* X  = (const float*)d_in[0];
  const int* pos  = (const int*)d_in[1];
  const float* Wq = (const float*)d_in[2];
  const float* Wk = (const float*)d_in[3];
  const float* Wv = (const float*)d_in[4];
  const float* Wo = (const float*)d_in[5];
  float* out = (float*)d_out;

  char* ws = (char*)d_ws;
  u16* Xb = (u16*)ws;                                    // 8 MB (reused as Vt later)
  u16* Vt = (u16*)ws;                                    // aliases Xb (dead after QKV gemm)
  u16* Wb = (u16*)(ws + (size_t)8*1024*1024);            // 4 x 2 MB (q,k,v,o)
  u16* Qb = (u16*)(ws + (size_t)16*1024*1024);           // 8 MB
  u16* Kb = Qb + (size_t)BT*DM;                          // 8 MB
  u16* Vb = Kb + (size_t)BT*DM;                          // 8 MB
  u16* Ob = (u16*)(ws + (size_t)40*1024*1024);           // 8 MB

  const int DD = DM*DM;
  cvt_all_kernel<<<8192, 256, 0, stream>>>(X, Wq, Wk, Wv, Wo, Xb, Wb);

  gemm_qkv<<<dim3(24, 32), 256, 0, stream>>>(Xb, Wb, Qb);
  rope_vt_kernel<<<1536, 256, 0, stream>>>(Qb, Kb, pos, Vb, Vt);
  attn_kernel<<<dim3(32, 16), 512, 0, stream>>>(Qb, Kb, Vt, Ob);
  gemm_out64<<<dim3(8, 64), 256, 0, stream>>>(Ob, Wb + 3*DD, out);
}

// Round 15
// 113.158 us; speedup vs baseline: 1.0881x; 1.0881x over previous
//
#include <hip/hip_runtime.h>
#include <hip/hip_bf16.h>

#define BB 2
#define TT 2048
#define DM 1024
#define NH 16
#define HD 64
#define BT (BB*TT)
#define SC2 0.18033688011112042f   // 0.125 / ln(2)

typedef unsigned short u16;
typedef __attribute__((ext_vector_type(8))) short short8;
typedef __attribute__((ext_vector_type(4))) float f32x4;

__device__ __forceinline__ u16 f2b(float f){
  unsigned u = __builtin_bit_cast(unsigned, f);
  u += 0x7FFFu + ((u >> 16) & 1u);
  return (u16)(u >> 16);
}
__device__ __forceinline__ float b2f(u16 h){
  unsigned u = ((unsigned)h) << 16;
  return __builtin_bit_cast(float, u);
}

__device__ __forceinline__ void gll16(const u16* g, u16* l){
  __builtin_amdgcn_global_load_lds((const __attribute__((address_space(1))) void*)g,
                                   (__attribute__((address_space(3))) void*)l, 16, 0, 0);
}

// ---------------- fused f32 -> bf16 conversion (X + 4 weights) ----------------
__global__ __launch_bounds__(256) void cvt_all_kernel(const float* __restrict__ X,
                                                      const float* __restrict__ w0,
                                                      const float* __restrict__ w1,
                                                      const float* __restrict__ w2,
                                                      const float* __restrict__ w3,
                                                      u16* __restrict__ Xb,
                                                      u16* __restrict__ Wb){
  const int b = blockIdx.x;
  const float* src;
  u16* dst;
  int i;
  if (b < 4096){
    src = X; dst = Xb; i = b*256 + threadIdx.x;
  } else {
    const int bb = b - 4096;
    const int seg = bb >> 10;
    src = (seg==0)?w0:(seg==1)?w1:(seg==2)?w2:w3;
    dst = Wb + (size_t)seg*DM*DM;
    i = (bb & 1023)*256 + threadIdx.x;
  }
  const float4 v = *(const float4*)(src + (size_t)i*4);
  ushort4 o;
  o.x = f2b(v.x); o.y = f2b(v.y); o.z = f2b(v.z); o.w = f2b(v.w);
  *(ushort4*)(dst + (size_t)i*4) = o;
}

// ---- 128x128-tile LDS-staged GEMM (QKV), counted-vmcnt two-barrier pipeline ----
#define FRAG(buf, row) (*(const short8*)((buf) + (size_t)(row)*32 + ((g ^ (((row)>>1)&3))*8)))

__global__ __launch_bounds__(256) void gemm_qkv(const u16* __restrict__ A,
                                                const u16* __restrict__ W,
                                                u16* __restrict__ Ybf){
  __shared__ u16 sA0[4096], sB0[4096], sA1[4096], sB1[4096];
  const int tid = threadIdx.x;
  const int lane = tid & 63;
  const int wave = tid >> 6;
  const int r = lane & 15, g = lane >> 4;
  const int wr = wave >> 1, wc = wave & 1;
  const int m0 = blockIdx.y << 7;
  const int nn0 = blockIdx.x << 7;

  const int srow = tid >> 2;
  const int lcol = (((tid & 3) ^ ((srow >> 1) & 3))) * 8;

  const u16* gA0 = A + (size_t)(m0 + srow)*DM + lcol;
  const u16* gA1 = gA0 + (size_t)64*DM;
  const u16* gB0 = W + (size_t)(nn0 + srow)*DM + lcol;
  const u16* gB1 = gB0 + (size_t)64*DM;

  f32x4 acc[4][4];
  #pragma unroll
  for (int i=0;i<4;i++)
    #pragma unroll
    for (int j=0;j<4;j++) acc[i][j] = (f32x4){0.f,0.f,0.f,0.f};

#define STAGE(SA, SB, koff) { \
    gll16(gA0 + (koff), SA + (size_t)tid*8); \
    gll16(gA1 + (koff), SA + 2048 + (size_t)tid*8); \
    gll16(gB0 + (koff), SB + (size_t)tid*8); \
    gll16(gB1 + (koff), SB + 2048 + (size_t)tid*8); }

#define COMPUTE(SA, SB) { \
    short8 af[4], bf[4]; \
    _Pragma("unroll") \
    for (int f=0; f<4; f++){ \
      af[f] = FRAG(SA, wr*64 + f*16 + r); \
      bf[f] = FRAG(SB, wc*64 + f*16 + r); \
    } \
    _Pragma("unroll") \
    for (int fr=0; fr<4; fr++) \
      _Pragma("unroll") \
      for (int fn=0; fn<4; fn++) \
        acc[fr][fn] = __builtin_amdgcn_mfma_f32_16x16x32_bf16(af[fr], bf[fn], acc[fr][fn], 0,0,0); }

  STAGE(sA0, sB0, 0);
  STAGE(sA1, sB1, 32);
  asm volatile("" ::: "memory");

  for (int t = 0; t < 32; t += 2){
    asm volatile("s_waitcnt vmcnt(4)" ::: "memory");
    __builtin_amdgcn_s_barrier();
    COMPUTE(sA0, sB0);
    __builtin_amdgcn_s_barrier();
    if (t + 2 < 32) STAGE(sA0, sB0, (t+2)*32);
    if (t + 3 < 32){
      asm volatile("s_waitcnt vmcnt(4)" ::: "memory");
    } else {
      asm volatile("s_waitcnt vmcnt(0)" ::: "memory");
    }
    __builtin_amdgcn_s_barrier();
    COMPUTE(sA1, sB1);
    __builtin_amdgcn_s_barrier();
    if (t + 3 < 32) STAGE(sA1, sB1, (t+3)*32);
  }

  #pragma unroll
  for (int fr=0; fr<4; fr++){
    #pragma unroll
    for (int i=0;i<4;i++){
      const int m = m0 + wr*64 + fr*16 + g*4 + i;
      #pragma unroll
      for (int fn=0; fn<4; fn++){
        const int nn = nn0 + wc*64 + fn*16 + r;
        Ybf[(size_t)(nn >> 10)*BT*DM + (size_t)m*DM + (nn & 1023)] = f2b(acc[fr][fn][i]);
      }
    }
  }
#undef STAGE
#undef COMPUTE
}

// ---- 64x128-tile output GEMM (f32 out): grid (8,64) -> 2 blocks/CU ----
__global__ __launch_bounds__(256) void gemm_out64(const u16* __restrict__ A,
                                                  const u16* __restrict__ W,
                                                  float* __restrict__ Yf){
  __shared__ u16 sA0[2048], sB0[4096], sA1[2048], sB1[4096];
  const int tid = threadIdx.x;
  const int lane = tid & 63;
  const int wave = tid >> 6;
  const int r = lane & 15, g = lane >> 4;
  const int wr = wave >> 1, wc = wave & 1;     // 2x2 waves over 64m x 128n
  const int m0 = blockIdx.y << 6;
  const int nn0 = blockIdx.x << 7;

  const int srow = tid >> 2;
  const int lcol = (((tid & 3) ^ ((srow >> 1) & 3))) * 8;

  const u16* gA0 = A + (size_t)(m0 + srow)*DM + lcol;
  const u16* gB0 = W + (size_t)(nn0 + srow)*DM + lcol;
  const u16* gB1 = gB0 + (size_t)64*DM;

  f32x4 acc[2][4];
  #pragma unroll
  for (int i=0;i<2;i++)
    #pragma unroll
    for (int j=0;j<4;j++) acc[i][j] = (f32x4){0.f,0.f,0.f,0.f};

#define STAGEO(SA, SB, koff) { \
    gll16(gA0 + (koff), SA + (size_t)tid*8); \
    gll16(gB0 + (koff), SB + (size_t)tid*8); \
    gll16(gB1 + (koff), SB + 2048 + (size_t)tid*8); }

#define COMPUTEO(SA, SB) { \
    short8 af[2], bf[4]; \
    _Pragma("unroll") \
    for (int f=0; f<2; f++) af[f] = FRAG(SA, wr*32 + f*16 + r); \
    _Pragma("unroll") \
    for (int f=0; f<4; f++) bf[f] = FRAG(SB, wc*64 + f*16 + r); \
    _Pragma("unroll") \
    for (int fr=0; fr<2; fr++) \
      _Pragma("unroll") \
      for (int fn=0; fn<4; fn++) \
        acc[fr][fn] = __builtin_amdgcn_mfma_f32_16x16x32_bf16(af[fr], bf[fn], acc[fr][fn], 0,0,0); }

  STAGEO(sA0, sB0, 0);
  STAGEO(sA1, sB1, 32);
  asm volatile("" ::: "memory");

  for (int t = 0; t < 32; t += 2){
    asm volatile("s_waitcnt vmcnt(3)" ::: "memory");
    __builtin_amdgcn_s_barrier();
    COMPUTEO(sA0, sB0);
    __builtin_amdgcn_s_barrier();
    if (t + 2 < 32) STAGEO(sA0, sB0, (t+2)*32);
    if (t + 3 < 32){
      asm volatile("s_waitcnt vmcnt(3)" ::: "memory");
    } else {
      asm volatile("s_waitcnt vmcnt(0)" ::: "memory");
    }
    __builtin_amdgcn_s_barrier();
    COMPUTEO(sA1, sB1);
    __builtin_amdgcn_s_barrier();
    if (t + 3 < 32) STAGEO(sA1, sB1, (t+3)*32);
  }

  #pragma unroll
  for (int fr=0; fr<2; fr++){
    #pragma unroll
    for (int i=0;i<4;i++){
      const int m = m0 + wr*32 + fr*16 + g*4 + i;
      #pragma unroll
      for (int fn=0; fn<4; fn++){
        const int nn = nn0 + wc*64 + fn*16 + r;
        Yf[(size_t)m*DM + nn] = acc[fr][fn][i];
      }
    }
  }
#undef STAGEO
#undef COMPUTEO
}

// ------- fused RoPE (blocks 0..511, Q pre-scaled) + V transpose (512..1535) -------
__global__ __launch_bounds__(256) void rope_vt_kernel(u16* __restrict__ Qb,
                                                      u16* __restrict__ Kb,
                                                      const int* __restrict__ pos,
                                                      const u16* __restrict__ Vb,
                                                      u16* __restrict__ Vt){
  __shared__ u16 tile[64][72];
  if (blockIdx.x < 512){
    const int t = blockIdx.x*256 + threadIdx.x;
    const int m = t >> 5;
    const int fi = t & 31;
    const float invf = __expf(-(float)fi * 0.28782313662425575f);
    float s, c;
    sincosf((float)pos[m] * invf, &s, &c);
    const float cq = c*SC2, sq = s*SC2;
    const size_t base = (size_t)m*DM + fi*2;
    #pragma unroll
    for (int h=0; h<NH; h++){
      const size_t a = base + h*HD;
      {
        const float x0 = b2f(Qb[a]), x1 = b2f(Qb[a+1]);
        Qb[a]   = f2b(cq*x0 - sq*x1);
        Qb[a+1] = f2b(cq*x1 + sq*x0);
      }
      {
        const float x0 = b2f(Kb[a]), x1 = b2f(Kb[a+1]);
        Kb[a]   = f2b(c*x0 - s*x1);
        Kb[a+1] = f2b(c*x1 + s*x0);
      }
    }
  } else {
    const int bidx = blockIdx.x - 512;
    const int bh = bidx >> 5;
    const int sc = bidx & 31;
    const int bq = bh >> 4, h = bh & 15;
    const int s0 = sc*64;
    {
      const int row = threadIdx.x >> 3;
      const int c8 = (threadIdx.x & 7)*8;
      #pragma unroll
      for (int rr = 0; rr < 64; rr += 32){
        const short8 v = *(const short8*)(Vb + (size_t)(bq*TT + s0 + row + rr)*DM + h*HD + c8);
        *(short8*)(&tile[row+rr][c8]) = v;
      }
    }
    __syncthreads();
    {
      const int d = threadIdx.x >> 3;
      const int s8 = (threadIdx.x & 7)*8;
      #pragma unroll
      for (int dd = 0; dd < 64; dd += 32){
        short8 ov;
        #pragma unroll
        for (int j=0;j<8;j++){
          const int sl = s8 + j;
          const int w = sl & 31;
          const int slog = (sl & 32) + (w >> 1) + ((w & 1) << 4);
          ov[j] = (short)tile[slog][d+dd];
        }
        *(short8*)(Vt + ((size_t)bh*HD + d + dd)*TT + s0 + s8) = ov;
      }
    }
  }
}

// ---------- causal flash attention: 8-wave blocks, 2-buf counted-vmcnt ----------
// row-sum via extra MFMA with all-ones B fragment (o4) -- no VALU lsum bookkeeping.
template<bool MASKED>
__device__ __forceinline__ void proc_fast(
    const short8 qf0, const short8 qf1,
    const short8 k00, const short8 k01, const short8 k10, const short8 k11,
    const short8 v0, const short8 v1, const short8 v2, const short8 v3,
    const short8 ones,
    f32x4& o0, f32x4& o1, f32x4& o2, f32x4& o3, f32x4& o4,
    const int q0, const int s0, const int r, const int g,
    u16 (*pbuf)[40])
{
  f32x4 sa0={0,0,0,0}, sa1={0,0,0,0};
  __builtin_amdgcn_s_setprio(1);
  sa0 = __builtin_amdgcn_mfma_f32_16x16x32_bf16(qf0, k00, sa0, 0,0,0);
  sa0 = __builtin_amdgcn_mfma_f32_16x16x32_bf16(qf1, k01, sa0, 0,0,0);
  sa1 = __builtin_amdgcn_mfma_f32_16x16x32_bf16(qf0, k10, sa1, 0,0,0);
  sa1 = __builtin_amdgcn_mfma_f32_16x16x32_bf16(qf1, k11, sa1, 0,0,0);
  __builtin_amdgcn_s_setprio(0);
  #pragma unroll
  for (int i=0;i<4;i++){
    float a = sa0[i], b = sa1[i];
    if (MASKED){
      const int q = q0 + g*4 + i;
      a = (s0 + r      <= q) ? a : -3.0e38f;
      b = (s0 + 16 + r <= q) ? b : -3.0e38f;
    }
    const float p0 = exp2f(a);
    const float p1 = exp2f(b);
    unsigned w;
    asm("v_cvt_pk_bf16_f32 %0, %1, %2" : "=v"(w) : "v"(p0), "v"(p1));
    *(unsigned*)(&pbuf[g*4+i][r*2]) = w;   // keys r (lo half), 16+r (hi half) interleaved
  }
  const short8 pf = *(const short8*)(&pbuf[r][g*8]);
  __builtin_amdgcn_s_setprio(1);
  o0 = __builtin_amdgcn_mfma_f32_16x16x32_bf16(pf, v0, o0, 0,0,0);
  o1 = __builtin_amdgcn_mfma_f32_16x16x32_bf16(pf, v1, o1, 0,0,0);
  o2 = __builtin_amdgcn_mfma_f32_16x16x32_bf16(pf, v2, o2, 0,0,0);
  o3 = __builtin_amdgcn_mfma_f32_16x16x32_bf16(pf, v3, o3, 0,0,0);
  o4 = __builtin_amdgcn_mfma_f32_16x16x32_bf16(pf, ones, o4, 0,0,0);  // row-sum of P
  __builtin_amdgcn_s_setprio(0);
}

__global__ __launch_bounds__(512) void attn_kernel(const u16* __restrict__ Qb,
                                                   const u16* __restrict__ Kb,
                                                   const u16* __restrict__ Vt,
                                                   u16* __restrict__ Ob){
  __shared__ u16 KVs[2][8192];       // 2-deep: [buf][ K: 64x64 | V: 64x64 ], slot-swizzled
  __shared__ u16 Plds[8][16][40];
  const int tid = threadIdx.x;
  const int lane = tid & 63;
  const int wave = tid >> 6;         // 0..7
  const int wq = wave & 3;           // q-row group
  const int par = wave >> 2;         // KV-half parity
  const int r = lane & 15, g = lane >> 4;

  const int bh = blockIdx.x;             // 0..31  (fast dim -> XCD L2 locality)
  const int pp = blockIdx.y;             // 0..15  (panel pair)
  const int bq = bh >> 4, h = bh & 15;
  const int lo = pp, hi = 31 - pp;
  const int w0A = lo*64 + wq*16;
  const int w0B = hi*64 + wq*16;
  const int sAd = (w0A >> 5) << 5;       // diagonal 32-block start for tile A
  const int sBd = (w0B >> 5) << 5;
  const int nb = hi + 1;                 // 64-row KV stage iterations (>=17)

  const short8 ones = {0x3F80,0x3F80,0x3F80,0x3F80,0x3F80,0x3F80,0x3F80,0x3F80}; // bf16 1.0

  // ---- Q fragments (pre-scaled by SC2 in rope) ----
  const u16* QrowA = Qb + (size_t)(bq*TT + w0A + r)*DM + h*HD;
  const u16* QrowB = Qb + (size_t)(bq*TT + w0B + r)*DM + h*HD;
  const short8 qA0 = *(const short8*)(QrowA + g*8);
  const short8 qA1 = *(const short8*)(QrowA + 32 + g*8);
  const short8 qB0 = *(const short8*)(QrowB + g*8);
  const short8 qB1 = *(const short8*)(QrowB + 32 + g*8);

  // ---- staging sources (pre-swizzled): 512 threads, 1 gll16 each for K and V ----
  const int srow = tid >> 3;                      // 0..63
  const int scol = ((tid & 7) ^ (srow & 7)) * 8;
  const u16* Ksrc = Kb + (size_t)(bq*TT + srow)*DM + h*HD + scol;
  const u16* Vsrc = Vt + (size_t)bh*HD*TT + (size_t)srow*TT + scol;

  f32x4 oA0={0,0,0,0}, oA1={0,0,0,0}, oA2={0,0,0,0}, oA3={0,0,0,0}, oA4={0,0,0,0};
  f32x4 oB0={0,0,0,0}, oB1={0,0,0,0}, oB2={0,0,0,0}, oB3={0,0,0,0}, oB4={0,0,0,0};

#define STAGEKV(B, S64) { \
    gll16(Ksrc + (size_t)(S64)*DM, &KVs[B][0]    + (size_t)tid*8); \
    gll16(Vsrc + (S64),            &KVs[B][4096] + (size_t)tid*8); }

  STAGEKV(0, 0);
  STAGEKV(1, 64);              // nb >= 17 always
  asm volatile("" ::: "memory");

  for (int ib = 0; ib < nb; ib++){
    const int cur = ib & 1;
    if (ib + 1 < nb){
      asm volatile("s_waitcnt vmcnt(2)" ::: "memory");
    } else {
      asm volatile("s_waitcnt vmcnt(0)" ::: "memory");
    }
    __builtin_amdgcn_s_barrier();

    const int s0 = ib*64 + par*32;         // this wave's 32-key half
    if (s0 <= sBd){
      const u16* kb_ = KVs[cur];
      const u16* vb_ = KVs[cur] + 4096;
      const int rb = par*32 + r;
      const int ph0 = (g ^ (r & 7))*8;
      const int ph1 = ((g + 4) ^ (r & 7))*8;
      const short8 k00 = *(const short8*)(kb_ + (size_t)rb*64 + ph0);
      const short8 k01 = *(const short8*)(kb_ + (size_t)rb*64 + ph1);
      const short8 k10 = *(const short8*)(kb_ + (size_t)(rb+16)*64 + ph0);
      const short8 k11 = *(const short8*)(kb_ + (size_t)(rb+16)*64 + ph1);
      const int vc = ((par*4 + g) ^ (r & 7))*8;
      const short8 v0 = *(const short8*)(vb_ + (size_t)(r     )*64 + vc);
      const short8 v1 = *(const short8*)(vb_ + (size_t)(16 + r)*64 + vc);
      const short8 v2 = *(const short8*)(vb_ + (size_t)(32 + r)*64 + vc);
      const short8 v3 = *(const short8*)(vb_ + (size_t)(48 + r)*64 + vc);
      if (s0 <= sAd){
        if (s0 == sAd) proc_fast<true >(qA0,qA1,k00,k01,k10,k11,v0,v1,v2,v3,ones,
                                        oA0,oA1,oA2,oA3,oA4,w0A,s0,r,g,Plds[wave]);
        else           proc_fast<false>(qA0,qA1,k00,k01,k10,k11,v0,v1,v2,v3,ones,
                                        oA0,oA1,oA2,oA3,oA4,w0A,s0,r,g,Plds[wave]);
      }
      if (s0 == sBd) proc_fast<true >(qB0,qB1,k00,k01,k10,k11,v0,v1,v2,v3,ones,
                                      oB0,oB1,oB2,oB3,oB4,w0B,s0,r,g,Plds[wave]);
      else           proc_fast<false>(qB0,qB1,k00,k01,k10,k11,v0,v1,v2,v3,ones,
                                      oB0,oB1,oB2,oB3,oB4,w0B,s0,r,g,Plds[wave]);
    }
    __builtin_amdgcn_s_barrier();
    if (ib + 2 < nb) STAGEKV(cur, (ib + 2)*64);
  }
#undef STAGEKV

  // ---- parity merge (pure sums; m==0 so no max/exp needed) ----
  __syncthreads();
  float* scr = (float*)&KVs[0][0];           // 20 KB scratch per phase
  const int mbase = wq*20*64 + lane;
  if (par == 1){
    #pragma unroll
    for (int i=0;i<4;i++){
      scr[mbase + (0*4+i)*64] = oA0[i];
      scr[mbase + (1*4+i)*64] = oA1[i];
      scr[mbase + (2*4+i)*64] = oA2[i];
      scr[mbase + (3*4+i)*64] = oA3[i];
      scr[mbase + (16+i)*64]  = oA4[i];
    }
  }
  __syncthreads();
  if (par == 0){
    #pragma unroll
    for (int i=0;i<4;i++){
      oA0[i] += scr[mbase + (0*4+i)*64];
      oA1[i] += scr[mbase + (1*4+i)*64];
      oA2[i] += scr[mbase + (2*4+i)*64];
      oA3[i] += scr[mbase + (3*4+i)*64];
      oA4[i] += scr[mbase + (16+i)*64];
    }
  }
  __syncthreads();
  if (par == 1){
    #pragma unroll
    for (int i=0;i<4;i++){
      scr[mbase + (0*4+i)*64] = oB0[i];
      scr[mbase + (1*4+i)*64] = oB1[i];
      scr[mbase + (2*4+i)*64] = oB2[i];
      scr[mbase + (3*4+i)*64] = oB3[i];
      scr[mbase + (16+i)*64]  = oB4[i];
    }
  }
  __syncthreads();
  if (par == 0){
    #pragma unroll
    for (int i=0;i<4;i++){
      oB0[i] += scr[mbase + (0*4+i)*64];
      oB1[i] += scr[mbase + (1*4+i)*64];
      oB2[i] += scr[mbase + (2*4+i)*64];
      oB3[i] += scr[mbase + (3*4+i)*64];
      oB4[i] += scr[mbase + (16+i)*64];
    }
    float invA[4], invB[4];
    #pragma unroll
    for (int i=0;i<4;i++){ invA[i] = 1.0f/oA4[i]; invB[i] = 1.0f/oB4[i]; }
    #pragma unroll
    for (int i=0;i<4;i++){
      const size_t rowA = (size_t)(bq*TT + w0A + g*4 + i)*DM + h*HD;
      Ob[rowA + r]      = f2b(oA0[i]*invA[i]);
      Ob[rowA + 16 + r] = f2b(oA1[i]*invA[i]);
      Ob[rowA + 32 + r] = f2b(oA2[i]*invA[i]);
      Ob[rowA + 48 + r] = f2b(oA3[i]*invA[i]);
      const size_t rowB = (size_t)(bq*TT + w0B + g*4 + i)*DM + h*HD;
      Ob[rowB + r]      = f2b(oB0[i]*invB[i]);
      Ob[rowB + 16 + r] = f2b(oB1[i]*invB[i]);
      Ob[rowB + 32 + r] = f2b(oB2[i]*invB[i]);
      Ob[rowB + 48 + r] = f2b(oB3[i]*invB[i]);
    }
  }
}

extern "C" void kernel_launch(void* const* d_in, const int* in_sizes, int n_in,
                              void* d_out, int out_size, void* d_ws, size_t ws_size,
                              hipStream_t stream) {
  const float* X  = (const float*)d_in[0];
  const int* pos  = (const int*)d_in[1];
  const float* Wq = (const float*)d_in[2];
  const float* Wk = (const float*)d_in[3];
  const float* Wv = (const float*)d_in[4];
  const float* Wo = (const float*)d_in[5];
  float* out = (float*)d_out;

  char* ws = (char*)d_ws;
  u16* Xb = (u16*)ws;                                    // 8 MB (reused as Vt later)
  u16* Vt = (u16*)ws;                                    // aliases Xb (dead after QKV gemm)
  u16* Wb = (u16*)(ws + (size_t)8*1024*1024);            // 4 x 2 MB (q,k,v,o)
  u16* Qb = (u16*)(ws + (size_t)16*1024*1024);           // 8 MB
  u16* Kb = Qb + (size_t)BT*DM;                          // 8 MB
  u16* Vb = Kb + (size_t)BT*DM;                          // 8 MB
  u16* Ob = (u16*)(ws + (size_t)40*1024*1024);           // 8 MB

  const int DD = DM*DM;
  cvt_all_kernel<<<8192, 256, 0, stream>>>(X, Wq, Wk, Wv, Wo, Xb, Wb);

  gemm_qkv<<<dim3(24, 32), 256, 0, stream>>>(Xb, Wb, Qb);
  rope_vt_kernel<<<1536, 256, 0, stream>>>(Qb, Kb, pos, Vb, Vt);
  attn_kernel<<<dim3(32, 16), 512, 0, stream>>>(Qb, Kb, Vt, Ob);
  gemm_out64<<<dim3(8, 64), 256, 0, stream>>>(Ob, Wb + 3*DD, out);
}

// Round 16
// 111.552 us; speedup vs baseline: 1.1037x; 1.0144x over previous
//
#include <hip/hip_runtime.h>
#include <hip/hip_bf16.h>

#define BB 2
#define TT 2048
#define DM 1024
#define NH 16
#define HD 64
#define BT (BB*TT)
#define SC2 0.18033688011112042f   // 0.125 / ln(2)

typedef unsigned short u16;
typedef __attribute__((ext_vector_type(8))) short short8;
typedef __attribute__((ext_vector_type(4))) float f32x4;

__device__ __forceinline__ u16 f2b(float f){
  unsigned u = __builtin_bit_cast(unsigned, f);
  u += 0x7FFFu + ((u >> 16) & 1u);
  return (u16)(u >> 16);
}
__device__ __forceinline__ float b2f(u16 h){
  unsigned u = ((unsigned)h) << 16;
  return __builtin_bit_cast(float, u);
}

__device__ __forceinline__ void gll16(const u16* g, u16* l){
  __builtin_amdgcn_global_load_lds((const __attribute__((address_space(1))) void*)g,
                                   (__attribute__((address_space(3))) void*)l, 16, 0, 0);
}

// ------- fused f32 -> bf16 conversion (X + 4 weights), 8 elems/thread -------
__global__ __launch_bounds__(256) void cvt_all_kernel(const float* __restrict__ X,
                                                      const float* __restrict__ w0,
                                                      const float* __restrict__ w1,
                                                      const float* __restrict__ w2,
                                                      const float* __restrict__ w3,
                                                      u16* __restrict__ Xb,
                                                      u16* __restrict__ Wb){
  const int b = blockIdx.x;
  const float* src;
  u16* dst;
  int i;
  if (b < 2048){                         // X: 524288 groups of 8
    src = X; dst = Xb; i = b*256 + threadIdx.x;
  } else {
    const int bb = b - 2048;
    const int seg = bb >> 9;             // 512 blocks per weight
    src = (seg==0)?w0:(seg==1)?w1:(seg==2)?w2:w3;
    dst = Wb + (size_t)seg*DM*DM;
    i = (bb & 511)*256 + threadIdx.x;
  }
  const float4 v0 = *(const float4*)(src + (size_t)i*8);
  const float4 v1 = *(const float4*)(src + (size_t)i*8 + 4);
  ushort4 o0, o1;
  o0.x = f2b(v0.x); o0.y = f2b(v0.y); o0.z = f2b(v0.z); o0.w = f2b(v0.w);
  o1.x = f2b(v1.x); o1.y = f2b(v1.y); o1.z = f2b(v1.z); o1.w = f2b(v1.w);
  *(ushort4*)(dst + (size_t)i*8)     = o0;
  *(ushort4*)(dst + (size_t)i*8 + 4) = o1;
}

// ---- 128x128-tile LDS-staged GEMM (QKV), counted-vmcnt two-barrier pipeline ----
#define FRAG(buf, row) (*(const short8*)((buf) + (size_t)(row)*32 + ((g ^ (((row)>>1)&3))*8)))

__global__ __launch_bounds__(256) void gemm_qkv(const u16* __restrict__ A,
                                                const u16* __restrict__ W,
                                                u16* __restrict__ Ybf){
  __shared__ u16 sA0[4096], sB0[4096], sA1[4096], sB1[4096];
  const int tid = threadIdx.x;
  const int lane = tid & 63;
  const int wave = tid >> 6;
  const int r = lane & 15, g = lane >> 4;
  const int wr = wave >> 1, wc = wave & 1;
  const int m0 = blockIdx.y << 7;
  const int nn0 = blockIdx.x << 7;

  const int srow = tid >> 2;
  const int lcol = (((tid & 3) ^ ((srow >> 1) & 3))) * 8;

  const u16* gA0 = A + (size_t)(m0 + srow)*DM + lcol;
  const u16* gA1 = gA0 + (size_t)64*DM;
  const u16* gB0 = W + (size_t)(nn0 + srow)*DM + lcol;
  const u16* gB1 = gB0 + (size_t)64*DM;

  f32x4 acc[4][4];
  #pragma unroll
  for (int i=0;i<4;i++)
    #pragma unroll
    for (int j=0;j<4;j++) acc[i][j] = (f32x4){0.f,0.f,0.f,0.f};

#define STAGE(SA, SB, koff) { \
    gll16(gA0 + (koff), SA + (size_t)tid*8); \
    gll16(gA1 + (koff), SA + 2048 + (size_t)tid*8); \
    gll16(gB0 + (koff), SB + (size_t)tid*8); \
    gll16(gB1 + (koff), SB + 2048 + (size_t)tid*8); }

#define COMPUTE(SA, SB) { \
    short8 af[4], bf[4]; \
    _Pragma("unroll") \
    for (int f=0; f<4; f++){ \
      af[f] = FRAG(SA, wr*64 + f*16 + r); \
      bf[f] = FRAG(SB, wc*64 + f*16 + r); \
    } \
    _Pragma("unroll") \
    for (int fr=0; fr<4; fr++) \
      _Pragma("unroll") \
      for (int fn=0; fn<4; fn++) \
        acc[fr][fn] = __builtin_amdgcn_mfma_f32_16x16x32_bf16(af[fr], bf[fn], acc[fr][fn], 0,0,0); }

  STAGE(sA0, sB0, 0);
  STAGE(sA1, sB1, 32);
  asm volatile("" ::: "memory");

  for (int t = 0; t < 32; t += 2){
    asm volatile("s_waitcnt vmcnt(4)" ::: "memory");
    __builtin_amdgcn_s_barrier();
    COMPUTE(sA0, sB0);
    __builtin_amdgcn_s_barrier();
    if (t + 2 < 32) STAGE(sA0, sB0, (t+2)*32);
    if (t + 3 < 32){
      asm volatile("s_waitcnt vmcnt(4)" ::: "memory");
    } else {
      asm volatile("s_waitcnt vmcnt(0)" ::: "memory");
    }
    __builtin_amdgcn_s_barrier();
    COMPUTE(sA1, sB1);
    __builtin_amdgcn_s_barrier();
    if (t + 3 < 32) STAGE(sA1, sB1, (t+3)*32);
  }

  #pragma unroll
  for (int fr=0; fr<4; fr++){
    #pragma unroll
    for (int i=0;i<4;i++){
      const int m = m0 + wr*64 + fr*16 + g*4 + i;
      #pragma unroll
      for (int fn=0; fn<4; fn++){
        const int nn = nn0 + wc*64 + fn*16 + r;
        Ybf[(size_t)(nn >> 10)*BT*DM + (size_t)m*DM + (nn & 1023)] = f2b(acc[fr][fn][i]);
      }
    }
  }
#undef STAGE
#undef COMPUTE
}

// ---- 64x128-tile output GEMM (f32 out): grid (8,64) -> 2 blocks/CU ----
__global__ __launch_bounds__(256) void gemm_out64(const u16* __restrict__ A,
                                                  const u16* __restrict__ W,
                                                  float* __restrict__ Yf){
  __shared__ u16 sA0[2048], sB0[4096], sA1[2048], sB1[4096];
  const int tid = threadIdx.x;
  const int lane = tid & 63;
  const int wave = tid >> 6;
  const int r = lane & 15, g = lane >> 4;
  const int wr = wave >> 1, wc = wave & 1;     // 2x2 waves over 64m x 128n
  const int m0 = blockIdx.y << 6;
  const int nn0 = blockIdx.x << 7;

  const int srow = tid >> 2;
  const int lcol = (((tid & 3) ^ ((srow >> 1) & 3))) * 8;

  const u16* gA0 = A + (size_t)(m0 + srow)*DM + lcol;
  const u16* gB0 = W + (size_t)(nn0 + srow)*DM + lcol;
  const u16* gB1 = gB0 + (size_t)64*DM;

  f32x4 acc[2][4];
  #pragma unroll
  for (int i=0;i<2;i++)
    #pragma unroll
    for (int j=0;j<4;j++) acc[i][j] = (f32x4){0.f,0.f,0.f,0.f};

#define STAGEO(SA, SB, koff) { \
    gll16(gA0 + (koff), SA + (size_t)tid*8); \
    gll16(gB0 + (koff), SB + (size_t)tid*8); \
    gll16(gB1 + (koff), SB + 2048 + (size_t)tid*8); }

#define COMPUTEO(SA, SB) { \
    short8 af[2], bf[4]; \
    _Pragma("unroll") \
    for (int f=0; f<2; f++) af[f] = FRAG(SA, wr*32 + f*16 + r); \
    _Pragma("unroll") \
    for (int f=0; f<4; f++) bf[f] = FRAG(SB, wc*64 + f*16 + r); \
    _Pragma("unroll") \
    for (int fr=0; fr<2; fr++) \
      _Pragma("unroll") \
      for (int fn=0; fn<4; fn++) \
        acc[fr][fn] = __builtin_amdgcn_mfma_f32_16x16x32_bf16(af[fr], bf[fn], acc[fr][fn], 0,0,0); }

  STAGEO(sA0, sB0, 0);
  STAGEO(sA1, sB1, 32);
  asm volatile("" ::: "memory");

  for (int t = 0; t < 32; t += 2){
    asm volatile("s_waitcnt vmcnt(3)" ::: "memory");
    __builtin_amdgcn_s_barrier();
    COMPUTEO(sA0, sB0);
    __builtin_amdgcn_s_barrier();
    if (t + 2 < 32) STAGEO(sA0, sB0, (t+2)*32);
    if (t + 3 < 32){
      asm volatile("s_waitcnt vmcnt(3)" ::: "memory");
    } else {
      asm volatile("s_waitcnt vmcnt(0)" ::: "memory");
    }
    __builtin_amdgcn_s_barrier();
    COMPUTEO(sA1, sB1);
    __builtin_amdgcn_s_barrier();
    if (t + 3 < 32) STAGEO(sA1, sB1, (t+3)*32);
  }

  #pragma unroll
  for (int fr=0; fr<2; fr++){
    #pragma unroll
    for (int i=0;i<4;i++){
      const int m = m0 + wr*32 + fr*16 + g*4 + i;
      #pragma unroll
      for (int fn=0; fn<4; fn++){
        const int nn = nn0 + wc*64 + fn*16 + r;
        Yf[(size_t)m*DM + nn] = acc[fr][fn][i];
      }
    }
  }
#undef STAGEO
#undef COMPUTEO
}

// ------- fused RoPE (blocks 0..511, Q pre-scaled) + V transpose (512..1535) -------
__global__ __launch_bounds__(256) void rope_vt_kernel(u16* __restrict__ Qb,
                                                      u16* __restrict__ Kb,
                                                      const int* __restrict__ pos,
                                                      const u16* __restrict__ Vb,
                                                      u16* __restrict__ Vt){
  __shared__ u16 tile[64][72];
  if (blockIdx.x < 512){
    const int t = blockIdx.x*256 + threadIdx.x;
    const int m = t >> 5;
    const int fi = t & 31;
    const float invf = __expf(-(float)fi * 0.28782313662425575f);
    float s, c;
    sincosf((float)pos[m] * invf, &s, &c);
    const float cq = c*SC2, sq = s*SC2;
    const size_t base = (size_t)m*DM + fi*2;
    #pragma unroll
    for (int h=0; h<NH; h++){
      const size_t a = base + h*HD;
      {
        const float x0 = b2f(Qb[a]), x1 = b2f(Qb[a+1]);
        Qb[a]   = f2b(cq*x0 - sq*x1);
        Qb[a+1] = f2b(cq*x1 + sq*x0);
      }
      {
        const float x0 = b2f(Kb[a]), x1 = b2f(Kb[a+1]);
        Kb[a]   = f2b(c*x0 - s*x1);
        Kb[a+1] = f2b(c*x1 + s*x0);
      }
    }
  } else {
    const int bidx = blockIdx.x - 512;
    const int bh = bidx >> 5;
    const int sc = bidx & 31;
    const int bq = bh >> 4, h = bh & 15;
    const int s0 = sc*64;
    {
      const int row = threadIdx.x >> 3;
      const int c8 = (threadIdx.x & 7)*8;
      #pragma unroll
      for (int rr = 0; rr < 64; rr += 32){
        const short8 v = *(const short8*)(Vb + (size_t)(bq*TT + s0 + row + rr)*DM + h*HD + c8);
        *(short8*)(&tile[row+rr][c8]) = v;
      }
    }
    __syncthreads();
    {
      const int d = threadIdx.x >> 3;
      const int s8 = (threadIdx.x & 7)*8;
      #pragma unroll
      for (int dd = 0; dd < 64; dd += 32){
        short8 ov;
        #pragma unroll
        for (int j=0;j<8;j++){
          const int sl = s8 + j;
          const int w = sl & 31;
          const int slog = (sl & 32) + (w >> 1) + ((w & 1) << 4);
          ov[j] = (short)tile[slog][d+dd];
        }
        *(short8*)(Vt + ((size_t)bh*HD + d + dd)*TT + s0 + s8) = ov;
      }
    }
  }
}

// ---------- causal flash attention: 8-wave blocks, 2-buf counted-vmcnt ----------
// row-sum via extra MFMA with all-ones B fragment (o4) -- no VALU lsum bookkeeping.
template<bool MASKED>
__device__ __forceinline__ void proc_fast(
    const short8 qf0, const short8 qf1,
    const short8 k00, const short8 k01, const short8 k10, const short8 k11,
    const short8 v0, const short8 v1, const short8 v2, const short8 v3,
    const short8 ones,
    f32x4& o0, f32x4& o1, f32x4& o2, f32x4& o3, f32x4& o4,
    const int q0, const int s0, const int r, const int g,
    u16 (*pbuf)[40])
{
  f32x4 sa0={0,0,0,0}, sa1={0,0,0,0};
  __builtin_amdgcn_s_setprio(1);
  sa0 = __builtin_amdgcn_mfma_f32_16x16x32_bf16(qf0, k00, sa0, 0,0,0);
  sa0 = __builtin_amdgcn_mfma_f32_16x16x32_bf16(qf1, k01, sa0, 0,0,0);
  sa1 = __builtin_amdgcn_mfma_f32_16x16x32_bf16(qf0, k10, sa1, 0,0,0);
  sa1 = __builtin_amdgcn_mfma_f32_16x16x32_bf16(qf1, k11, sa1, 0,0,0);
  __builtin_amdgcn_s_setprio(0);
  #pragma unroll
  for (int i=0;i<4;i++){
    float a = sa0[i], b = sa1[i];
    if (MASKED){
      const int q = q0 + g*4 + i;
      a = (s0 + r      <= q) ? a : -3.0e38f;
      b = (s0 + 16 + r <= q) ? b : -3.0e38f;
    }
    const float p0 = exp2f(a);
    const float p1 = exp2f(b);
    unsigned w;
    asm("v_cvt_pk_bf16_f32 %0, %1, %2" : "=v"(w) : "v"(p0), "v"(p1));
    *(unsigned*)(&pbuf[g*4+i][r*2]) = w;   // keys r (lo half), 16+r (hi half) interleaved
  }
  const short8 pf = *(const short8*)(&pbuf[r][g*8]);
  __builtin_amdgcn_s_setprio(1);
  o0 = __builtin_amdgcn_mfma_f32_16x16x32_bf16(pf, v0, o0, 0,0,0);
  o1 = __builtin_amdgcn_mfma_f32_16x16x32_bf16(pf, v1, o1, 0,0,0);
  o2 = __builtin_amdgcn_mfma_f32_16x16x32_bf16(pf, v2, o2, 0,0,0);
  o3 = __builtin_amdgcn_mfma_f32_16x16x32_bf16(pf, v3, o3, 0,0,0);
  o4 = __builtin_amdgcn_mfma_f32_16x16x32_bf16(pf, ones, o4, 0,0,0);  // row-sum of P
  __builtin_amdgcn_s_setprio(0);
}

__global__ __launch_bounds__(512) void attn_kernel(const u16* __restrict__ Qb,
                                                   const u16* __restrict__ Kb,
                                                   const u16* __restrict__ Vt,
                                                   u16* __restrict__ Ob){
  __shared__ u16 KVs[2][8192];       // 2-deep: [buf][ K: 64x64 | V: 64x64 ], slot-swizzled
  __shared__ u16 Plds[8][16][40];
  const int tid = threadIdx.x;
  const int lane = tid & 63;
  const int wave = tid >> 6;         // 0..7
  const int wq = wave & 3;           // q-row group
  const int par = wave >> 2;         // KV-half parity
  const int r = lane & 15, g = lane >> 4;

  const int bh = blockIdx.x;             // 0..31  (fast dim -> XCD L2 locality)
  const int ppo = blockIdx.y;            // 0..15
  // co-resident blocks (bh,ppo),(bh,ppo+8) -> pp pair sums to 49 stage-iters (constant)
  const int pp = (ppo < 8) ? ppo : (23 - ppo);
  const int bq = bh >> 4, h = bh & 15;
  const int lo = pp, hi = 31 - pp;
  const int w0A = lo*64 + wq*16;
  const int w0B = hi*64 + wq*16;
  const int sAd = (w0A >> 5) << 5;       // diagonal 32-block start for tile A
  const int sBd = (w0B >> 5) << 5;
  const int nb = hi + 1;                 // 64-row KV stage iterations (>=17)

  const short8 ones = {0x3F80,0x3F80,0x3F80,0x3F80,0x3F80,0x3F80,0x3F80,0x3F80}; // bf16 1.0

  // ---- Q fragments (pre-scaled by SC2 in rope) ----
  const u16* QrowA = Qb + (size_t)(bq*TT + w0A + r)*DM + h*HD;
  const u16* QrowB = Qb + (size_t)(bq*TT + w0B + r)*DM + h*HD;
  const short8 qA0 = *(const short8*)(QrowA + g*8);
  const short8 qA1 = *(const short8*)(QrowA + 32 + g*8);
  const short8 qB0 = *(const short8*)(QrowB + g*8);
  const short8 qB1 = *(const short8*)(QrowB + 32 + g*8);

  // ---- staging sources (pre-swizzled): 512 threads, 1 gll16 each for K and V ----
  const int srow = tid >> 3;                      // 0..63
  const int scol = ((tid & 7) ^ (srow & 7)) * 8;
  const u16* Ksrc = Kb + (size_t)(bq*TT + srow)*DM + h*HD + scol;
  const u16* Vsrc = Vt + (size_t)bh*HD*TT + (size_t)srow*TT + scol;

  f32x4 oA0={0,0,0,0}, oA1={0,0,0,0}, oA2={0,0,0,0}, oA3={0,0,0,0}, oA4={0,0,0,0};
  f32x4 oB0={0,0,0,0}, oB1={0,0,0,0}, oB2={0,0,0,0}, oB3={0,0,0,0}, oB4={0,0,0,0};

#define STAGEKV(B, S64) { \
    gll16(Ksrc + (size_t)(S64)*DM, &KVs[B][0]    + (size_t)tid*8); \
    gll16(Vsrc + (S64),            &KVs[B][4096] + (size_t)tid*8); }

  STAGEKV(0, 0);
  STAGEKV(1, 64);              // nb >= 17 always
  asm volatile("" ::: "memory");

  for (int ib = 0; ib < nb; ib++){
    const int cur = ib & 1;
    if (ib + 1 < nb){
      asm volatile("s_waitcnt vmcnt(2)" ::: "memory");
    } else {
      asm volatile("s_waitcnt vmcnt(0)" ::: "memory");
    }
    __builtin_amdgcn_s_barrier();

    const int s0 = ib*64 + par*32;         // this wave's 32-key half
    if (s0 <= sBd){
      const u16* kb_ = KVs[cur];
      const u16* vb_ = KVs[cur] + 4096;
      const int rb = par*32 + r;
      const int ph0 = (g ^ (r & 7))*8;
      const int ph1 = ((g + 4) ^ (r & 7))*8;
      const short8 k00 = *(const short8*)(kb_ + (size_t)rb*64 + ph0);
      const short8 k01 = *(const short8*)(kb_ + (size_t)rb*64 + ph1);
      const short8 k10 = *(const short8*)(kb_ + (size_t)(rb+16)*64 + ph0);
      const short8 k11 = *(const short8*)(kb_ + (size_t)(rb+16)*64 + ph1);
      const int vc = ((par*4 + g) ^ (r & 7))*8;
      const short8 v0 = *(const short8*)(vb_ + (size_t)(r     )*64 + vc);
      const short8 v1 = *(const short8*)(vb_ + (size_t)(16 + r)*64 + vc);
      const short8 v2 = *(const short8*)(vb_ + (size_t)(32 + r)*64 + vc);
      const short8 v3 = *(const short8*)(vb_ + (size_t)(48 + r)*64 + vc);
      if (s0 <= sAd){
        if (s0 == sAd) proc_fast<true >(qA0,qA1,k00,k01,k10,k11,v0,v1,v2,v3,ones,
                                        oA0,oA1,oA2,oA3,oA4,w0A,s0,r,g,Plds[wave]);
        else           proc_fast<false>(qA0,qA1,k00,k01,k10,k11,v0,v1,v2,v3,ones,
                                        oA0,oA1,oA2,oA3,oA4,w0A,s0,r,g,Plds[wave]);
      }
      if (s0 == sBd) proc_fast<true >(qB0,qB1,k00,k01,k10,k11,v0,v1,v2,v3,ones,
                                      oB0,oB1,oB2,oB3,oB4,w0B,s0,r,g,Plds[wave]);
      else           proc_fast<false>(qB0,qB1,k00,k01,k10,k11,v0,v1,v2,v3,ones,
                                      oB0,oB1,oB2,oB3,oB4,w0B,s0,r,g,Plds[wave]);
    }
    __builtin_amdgcn_s_barrier();
    if (ib + 2 < nb) STAGEKV(cur, (ib + 2)*64);
  }
#undef STAGEKV

  // ---- parity merge (pure sums; m==0 so no max/exp needed) ----
  __syncthreads();
  float* scr = (float*)&KVs[0][0];           // 20 KB scratch per phase
  const int mbase = wq*20*64 + lane;
  if (par == 1){
    #pragma unroll
    for (int i=0;i<4;i++){
      scr[mbase + (0*4+i)*64] = oA0[i];
      scr[mbase + (1*4+i)*64] = oA1[i];
      scr[mbase + (2*4+i)*64] = oA2[i];
      scr[mbase + (3*4+i)*64] = oA3[i];
      scr[mbase + (16+i)*64]  = oA4[i];
    }
  }
  __syncthreads();
  if (par == 0){
    #pragma unroll
    for (int i=0;i<4;i++){
      oA0[i] += scr[mbase + (0*4+i)*64];
      oA1[i] += scr[mbase + (1*4+i)*64];
      oA2[i] += scr[mbase + (2*4+i)*64];
      oA3[i] += scr[mbase + (3*4+i)*64];
      oA4[i] += scr[mbase + (16+i)*64];
    }
  }
  __syncthreads();
  if (par == 1){
    #pragma unroll
    for (int i=0;i<4;i++){
      scr[mbase + (0*4+i)*64] = oB0[i];
      scr[mbase + (1*4+i)*64] = oB1[i];
      scr[mbase + (2*4+i)*64] = oB2[i];
      scr[mbase + (3*4+i)*64] = oB3[i];
      scr[mbase + (16+i)*64]  = oB4[i];
    }
  }
  __syncthreads();
  if (par == 0){
    #pragma unroll
    for (int i=0;i<4;i++){
      oB0[i] += scr[mbase + (0*4+i)*64];
      oB1[i] += scr[mbase + (1*4+i)*64];
      oB2[i] += scr[mbase + (2*4+i)*64];
      oB3[i] += scr[mbase + (3*4+i)*64];
      oB4[i] += scr[mbase + (16+i)*64];
    }
    float invA[4], invB[4];
    #pragma unroll
    for (int i=0;i<4;i++){ invA[i] = 1.0f/oA4[i]; invB[i] = 1.0f/oB4[i]; }
    #pragma unroll
    for (int i=0;i<4;i++){
      const size_t rowA = (size_t)(bq*TT + w0A + g*4 + i)*DM + h*HD;
      Ob[rowA + r]      = f2b(oA0[i]*invA[i]);
      Ob[rowA + 16 + r] = f2b(oA1[i]*invA[i]);
      Ob[rowA + 32 + r] = f2b(oA2[i]*invA[i]);
      Ob[rowA + 48 + r] = f2b(oA3[i]*invA[i]);
      const size_t rowB = (size_t)(bq*TT + w0B + g*4 + i)*DM + h*HD;
      Ob[rowB + r]      = f2b(oB0[i]*invB[i]);
      Ob[rowB + 16 + r] = f2b(oB1[i]*invB[i]);
      Ob[rowB + 32 + r] = f2b(oB2[i]*invB[i]);
      Ob[rowB + 48 + r] = f2b(oB3[i]*invB[i]);
    }
  }
}

extern "C" void kernel_launch(void* const* d_in, const int* in_sizes, int n_in,
                              void* d_out, int out_size, void* d_ws, size_t ws_size,
                              hipStream_t stream) {
  const float* X  = (const float*)d_in[0];
  const int* pos  = (const int*)d_in[1];
  const float* Wq = (const float*)d_in[2];
  const float* Wk = (const float*)d_in[3];
  const float* Wv = (const float*)d_in[4];
  const float* Wo = (const float*)d_in[5];
  float* out = (float*)d_out;

  char* ws = (char*)d_ws;
  u16* Xb = (u16*)ws;                                    // 8 MB (reused as Vt later)
  u16* Vt = (u16*)ws;                                    // aliases Xb (dead after QKV gemm)
  u16* Wb = (u16*)(ws + (size_t)8*1024*1024);            // 4 x 2 MB (q,k,v,o)
  u16* Qb = (u16*)(ws + (size_t)16*1024*1024);           // 8 MB
  u16* Kb = Qb + (size_t)BT*DM;                          // 8 MB
  u16* Vb = Kb + (size_t)BT*DM;                          // 8 MB
  u16* Ob = (u16*)(ws + (size_t)40*1024*1024);           // 8 MB

  const int DD = DM*DM;
  cvt_all_kernel<<<4096, 256, 0, stream>>>(X, Wq, Wk, Wv, Wo, Xb, Wb);

  gemm_qkv<<<dim3(24, 32), 256, 0, stream>>>(Xb, Wb, Qb);
  rope_vt_kernel<<<1536, 256, 0, stream>>>(Qb, Kb, pos, Vb, Vt);
  attn_kernel<<<dim3(32, 16), 512, 0, stream>>>(Qb, Kb, Vt, Ob);
  gemm_out64<<<dim3(8, 64), 256, 0, stream>>>(Ob, Wb + 3*DD, out);
}